// Round 1
// baseline (231.950 us; speedup 1.0000x reference)
//
#include <hip/hip_runtime.h>
#include <hip/hip_bf16.h>
#include <stdint.h>

#define DI __device__ __forceinline__

using f32x4 = __attribute__((ext_vector_type(4))) float;
using s16x8 = __attribute__((ext_vector_type(8))) short;

#define BB 64
#define SS 400
#define HH 512
#define VVOC 32000
#define MTOT (BB*SS)   // 25600

// ---------- helpers ----------
DI short bf16r(float f){
  __hip_bfloat16 h = __float2bfloat16(f);
  union { __hip_bfloat16 h; short s; } u; u.h = h; return u.s;
}
DI float sigm(float x){ return 1.f/(1.f + __expf(-x)); }
DI float tanhfast(float x){ x = fminf(x, 12.f); float e = __expf(2.f*x); return (e-1.f)/(e+1.f); }

DI void gload16(const float* g, float* l){
  __builtin_amdgcn_global_load_lds(
      (const __attribute__((address_space(1))) float*)g,
      (__attribute__((address_space(3))) float*)l, 16, 0, 0);
}

DI float blkmax(float v, float* red, int t){
  #pragma unroll
  for (int o = 32; o; o >>= 1) v = fmaxf(v, __shfl_xor(v, o));
  if ((t & 63) == 0) red[t >> 6] = v;
  __syncthreads();
  v = fmaxf(fmaxf(red[0], red[1]), fmaxf(red[2], red[3]));
  __syncthreads();
  return v;
}
DI float blksum(float v, float* red, int t){
  #pragma unroll
  for (int o = 32; o; o >>= 1) v += __shfl_xor(v, o);
  if ((t & 63) == 0) red[t >> 6] = v;
  __syncthreads();
  v = red[0] + red[1] + red[2] + red[3];
  __syncthreads();
  return v;
}

// fragment load from f32 LDS tile (row stride 32 floats, 16B chunks XOR-swizzled by row&7)
DI s16x8 fragload(const float* tile, int rbase, int l){
  int kq = l >> 4;
  int rr = rbase + (l & 15);
  int swz = rr & 7;
  const float* base = tile + rr*32;
  f32x4 lo = *(const f32x4*)(base + (((2*kq    ) ^ swz) << 2));
  f32x4 hi = *(const f32x4*)(base + (((2*kq + 1) ^ swz) << 2));
  s16x8 o;
  o[0]=bf16r(lo[0]); o[1]=bf16r(lo[1]); o[2]=bf16r(lo[2]); o[3]=bf16r(lo[3]);
  o[4]=bf16r(hi[0]); o[5]=bf16r(hi[1]); o[6]=bf16r(hi[2]); o[7]=bf16r(hi[3]);
  return o;
}

// ---------- mask dtype detector (bool bytes vs int32) ----------
__global__ void detect_mask(const unsigned int* m, int nwords, int* flag){
  __shared__ int f;
  if (threadIdx.x == 0) f = 0;
  __syncthreads();
  int loc = 0;
  for (int i = threadIdx.x; i < nwords; i += blockDim.x) loc |= (m[i] > 1u) ? 1 : 0;
  if (loc) atomicOr(&f, 1);
  __syncthreads();
  if (threadIdx.x == 0) *flag = f;
}

// ---------- MFMA GEMM: C = A[M,K] * Bw[N,K]^T ; f32 in, bf16 MFMA ----------
// SCORE=true : fused epilogue  partial_score[r] += sum_h v[h]*tanh(P[r,h]+q[b,h])
// SCORE=false: dst[r*Ntot+c] = acc + vb[c]
template<int BM, int MREP, bool SCORE>
__global__ __launch_bounds__(256) void mfma_gemm(
    const float* __restrict__ A, const float* __restrict__ Bw, int K,
    const float* __restrict__ qv, const float* __restrict__ vb,
    float* __restrict__ dst, int Ntot)
{
  __shared__ __align__(16) float lsa[BM*32];
  __shared__ __align__(16) float lsb[128*32];
  const int t = threadIdx.x;
  const int l = t & 63;
  const int w = t >> 6;
  const int wm = w >> 1, wn = w & 1;
  const int mrow = blockIdx.x * BM;
  const int ncol = blockIdx.y * 128;

  f32x4 acc[MREP][4];
  #pragma unroll
  for (int m = 0; m < MREP; ++m)
    #pragma unroll
    for (int n = 0; n < 4; ++n) { f32x4 z = {0.f,0.f,0.f,0.f}; acc[m][n] = z; }

  for (int k0 = 0; k0 < K; k0 += 32) {
    #pragma unroll
    for (int i = 0; i < BM*8/256; ++i) {      // stage A tile (BM x 32 f32)
      int idx = i*256 + t;
      int r = idx >> 3, c = idx & 7;
      int cg = c ^ (r & 7);
      gload16(A + (size_t)(mrow + r)*K + k0 + cg*4, lsa + idx*4);
    }
    #pragma unroll
    for (int i = 0; i < 4; ++i) {             // stage B tile (128 x 32 f32)
      int idx = i*256 + t;
      int r = idx >> 3, c = idx & 7;
      int cg = c ^ (r & 7);
      gload16(Bw + (size_t)(ncol + r)*K + k0 + cg*4, lsb + idx*4);
    }
    __syncthreads();
    s16x8 bf[4];
    #pragma unroll
    for (int n = 0; n < 4; ++n) bf[n] = fragload(lsb, wn*64 + n*16, l);
    #pragma unroll
    for (int m = 0; m < MREP; ++m) {
      s16x8 af = fragload(lsa, wm*(MREP*16) + m*16, l);
      #pragma unroll
      for (int n = 0; n < 4; ++n)
        acc[m][n] = __builtin_amdgcn_mfma_f32_16x16x32_bf16(af, bf[n], acc[m][n], 0, 0, 0);
    }
    __syncthreads();
  }

  const int kq = l >> 4, lc = l & 15;
  if (SCORE) {
    float vv[4];
    #pragma unroll
    for (int n = 0; n < 4; ++n) vv[n] = vb[ncol + wn*64 + n*16 + lc];
    #pragma unroll
    for (int m = 0; m < MREP; ++m) {
      #pragma unroll
      for (int j = 0; j < 4; ++j) {
        int r = mrow + wm*(MREP*16) + m*16 + kq*4 + j;
        int b = r / SS;
        const float* qb = qv + b*HH + ncol + wn*64 + lc;
        float ps = 0.f;
        #pragma unroll
        for (int n = 0; n < 4; ++n) ps += vv[n]*tanhfast(acc[m][n][j] + qb[n*16]);
        #pragma unroll
        for (int o = 1; o < 16; o <<= 1) ps += __shfl_xor(ps, o);
        if (lc == 0) dst[(blockIdx.y*2 + wn)*MTOT + r] = ps;
      }
    }
  } else {
    #pragma unroll
    for (int m = 0; m < MREP; ++m)
      #pragma unroll
      for (int j = 0; j < 4; ++j) {
        int r = mrow + wm*(MREP*16) + m*16 + kq*4 + j;
        #pragma unroll
        for (int n = 0; n < 4; ++n) {
          int c = ncol + wn*64 + n*16 + lc;
          dst[(size_t)r*Ntot + c] = acc[m][n][j] + vb[c];
        }
      }
  }
}

// ---------- small f32 GEMM (M=64), K-split partials: P[seg] = A * W^T (K-range) ----------
__global__ __launch_bounds__(256) void sgemm_part(
    const float* __restrict__ A0, const float* __restrict__ A1,
    const float* __restrict__ W0, const float* __restrict__ W1,
    float* __restrict__ P0, float* __restrict__ P1,
    int K, int N, int KSEG)
{
  const float* A = blockIdx.z ? A1 : A0;
  const float* W = blockIdx.z ? W1 : W0;
  float*       P = blockIdx.z ? P1 : P0;
  __shared__ float sa[64][65];   // [k][b]
  __shared__ float sw[64][65];   // [c][k]
  int t = threadIdx.x;
  int bg = (t & 15) * 4, cg = (t >> 4) * 4;
  int c0 = blockIdx.x * 64;
  float acc[4][4] = {};
  int kbeg = blockIdx.y * KSEG;
  for (int kc = 0; kc < KSEG; kc += 64) {
    int kk = kbeg + kc;
    for (int i = t; i < 4096; i += 256) {
      int r = i >> 6, k = i & 63;
      sa[k][r] = A[(size_t)r*K + kk + k];
      sw[r][k] = W[(size_t)(c0 + r)*K + kk + k];
    }
    __syncthreads();
    #pragma unroll 8
    for (int k = 0; k < 64; ++k) {
      float av[4], wv[4];
      #pragma unroll
      for (int i = 0; i < 4; ++i) { av[i] = sa[k][bg+i]; wv[i] = sw[cg+i][k]; }
      #pragma unroll
      for (int i = 0; i < 4; ++i)
        #pragma unroll
        for (int j = 0; j < 4; ++j) acc[i][j] += av[i]*wv[j];
    }
    __syncthreads();
  }
  size_t pbase = (size_t)blockIdx.y * 64 * N;
  #pragma unroll
  for (int i = 0; i < 4; ++i)
    #pragma unroll
    for (int j = 0; j < 4; ++j)
      P[pbase + (size_t)(bg+i)*N + c0 + cg + j] = acc[i][j];
}

// ---------- combine 8 K-split partials + biases ----------
__global__ void combine8(const float* __restrict__ P, const float* __restrict__ b1,
                         const float* __restrict__ b2, float* __restrict__ dstv,
                         int N, int total)
{
  int i = blockIdx.x*256 + threadIdx.x;
  if (i >= total) return;
  float a = 0.f;
  #pragma unroll
  for (int s = 0; s < 8; ++s) a += P[(size_t)s*total + i];
  int c = i % N;
  if (b1) a += b1[c];
  if (b2) a += b2[c];
  dstv[i] = a;
}

// ---------- GRU gate combine ----------
__global__ void gru_gate(const float* __restrict__ GI, const float* __restrict__ GH,
                         const float* __restrict__ b_ih, const float* __restrict__ b_hh,
                         const float* __restrict__ hprev, float* __restrict__ hid,
                         float* __restrict__ concat)
{
  int i = blockIdx.x*256 + threadIdx.x;  // 0..32767
  int b = i >> 9, h = i & 511;
  float ir=0, iz=0, inn=0, hr=0, hz=0, hn=0;
  #pragma unroll
  for (int s = 0; s < 8; ++s) {
    const float* gi = GI + (size_t)s*(64*1536) + b*1536;
    const float* gh = GH + (size_t)s*(64*1536) + b*1536;
    ir += gi[h];      iz += gi[512+h];  inn += gi[1024+h];
    hr += gh[h];      hz += gh[512+h];  hn  += gh[1024+h];
  }
  ir += b_ih[h]; iz += b_ih[512+h]; inn += b_ih[1024+h];
  hr += b_hh[h]; hz += b_hh[512+h]; hn  += b_hh[1024+h];
  float r = sigm(ir + hr), z = sigm(iz + hz);
  float n = tanhfast(inn + r*hn);
  float hv = (1.f - z)*n + z*hprev[i];
  hid[i] = hv;
  concat[b*1536 + h] = hv;
}

// ---------- masked softmax over S ----------
__global__ void softmax_s(const float* __restrict__ part, const void* __restrict__ mask,
                          const int* __restrict__ flag, float* __restrict__ attn)
{
  __shared__ float red[4];
  int b = blockIdx.x, t = threadIdx.x;
  bool isbyte = (*flag != 0);
  float sc0, sc1 = -INFINITY;
  {
    float v = 0.f;
    #pragma unroll
    for (int p = 0; p < 8; ++p) v += part[p*MTOT + b*SS + t];
    bool mv = isbyte ? (((const unsigned char*)mask)[b*SS + t] != 0)
                     : (((const int*)mask)[b*SS + t] != 0);
    sc0 = mv ? v : -INFINITY;
  }
  int s1 = t + 256;
  if (s1 < SS) {
    float v = 0.f;
    #pragma unroll
    for (int p = 0; p < 8; ++p) v += part[p*MTOT + b*SS + s1];
    bool mv = isbyte ? (((const unsigned char*)mask)[b*SS + s1] != 0)
                     : (((const int*)mask)[b*SS + s1] != 0);
    sc1 = mv ? v : -INFINITY;
  }
  float mx = blkmax(fmaxf(sc0, sc1), red, t);
  float e0 = __expf(sc0 - mx), e1 = __expf(sc1 - mx);
  float sum = blksum(e0 + e1, red, t);
  float inv = 1.f / sum;
  attn[b*SS + t] = e0 * inv;
  if (s1 < SS) attn[b*SS + s1] = e1 * inv;
}

// ---------- context = attn @ enc ----------
__global__ void ctx_kernel(const float* __restrict__ attn, const float* __restrict__ enc,
                           float* __restrict__ ctx, float* __restrict__ concat)
{
  int b = blockIdx.x, dc = blockIdx.y;
  int d = dc*256 + threadIdx.x;
  const float* a = attn + b*SS;
  const float* e = enc + (size_t)b*SS*1024 + d;
  float s0=0,s1=0,s2=0,s3=0;
  for (int s = 0; s < SS; s += 4) {
    s0 += a[s  ]*e[(size_t)(s  )*1024];
    s1 += a[s+1]*e[(size_t)(s+1)*1024];
    s2 += a[s+2]*e[(size_t)(s+2)*1024];
    s3 += a[s+3]*e[(size_t)(s+3)*1024];
  }
  float tot = (s0+s1)+(s2+s3);
  ctx[b*1024 + d] = tot;
  concat[b*1536 + 512 + d] = tot;
}

// ---------- vocab softmax (in-place over logits in d_out) ----------
__global__ void vsoftmax(float* __restrict__ logits)
{
  __shared__ float red[4];
  int b = blockIdx.x, t = threadIdx.x;
  float* p = logits + (size_t)b * VVOC;
  float mx = -1e30f;
  for (int i = t; i < VVOC; i += 256) mx = fmaxf(mx, p[i]);
  mx = blkmax(mx, red, t);
  float sm = 0.f;
  for (int i = t; i < VVOC; i += 256) sm += __expf(p[i] - mx);
  sm = blksum(sm, red, t);
  float inv = 1.f / sm;
  for (int i = t; i < VVOC; i += 256) p[i] = __expf(p[i] - mx) * inv;
}

// ---------- launch ----------
extern "C" void kernel_launch(void* const* d_in, const int* in_sizes, int n_in,
                              void* d_out, int out_size, void* d_ws, size_t ws_size,
                              hipStream_t stream) {
  (void)in_sizes; (void)n_in; (void)out_size; (void)ws_size;
  const float* x      = (const float*)d_in[0];
  const float* hprev  = (const float*)d_in[1];
  const float* enc    = (const float*)d_in[2];
  const void*  mask   = d_in[3];
  const float* w_ih   = (const float*)d_in[4];
  const float* w_hh   = (const float*)d_in[5];
  const float* b_ih   = (const float*)d_in[6];
  const float* b_hh   = (const float*)d_in[7];
  const float* Wh_w   = (const float*)d_in[8];
  const float* Wh_b   = (const float*)d_in[9];
  const float* Ws_w   = (const float*)d_in[10];
  const float* Ws_b   = (const float*)d_in[11];
  const float* vatt   = (const float*)d_in[12];
  const float* V_w    = (const float*)d_in[13];
  const float* V_b    = (const float*)d_in[14];
  const float* Vhat_w = (const float*)d_in[15];
  const float* Vhat_b = (const float*)d_in[16];

  float* out   = (float*)d_out;
  float* vocab = out;                    // [64,32000]
  float* attn  = out + 2048000;          // [64,400]
  float* ctx   = out + 2073600;          // [64,1024]
  float* hid   = out + 2139136;          // [64,512]

  float* WS = (float*)d_ws;
  int*   flag   = (int*)d_ws;
  float* GI     = WS + 16;               // 8*64*1536
  float* GH     = GI + 786432;
  float* CONCAT = GH + 786432;           // 64*1536
  float* QP     = CONCAT + 98304;        // 8*64*512
  float* Q      = QP + 262144;           // 64*512
  float* OUTP   = Q + 32768;             // 8*64*512
  float* OUT    = OUTP + 262144;         // 64*512
  float* PART   = OUT + 32768;           // 8*25600

  detect_mask<<<1, 256, 0, stream>>>((const unsigned int*)mask, (BB*SS)/4, flag);

  // GRU input/hidden gate GEMMs (z=0: gi, z=1: gh), K=512 split 8
  sgemm_part<<<dim3(1536/64, 8, 2), 256, 0, stream>>>(x, hprev, w_ih, w_hh, GI, GH, 512, 1536, 64);
  gru_gate<<<dim3(128), 256, 0, stream>>>(GI, GH, b_ih, b_hh, hprev, hid, CONCAT);

  // q = hidden@Ws^T + Ws_b + Wh_b
  sgemm_part<<<dim3(8, 8, 1), 256, 0, stream>>>(hid, hid, Ws_w, Ws_w, QP, QP, 512, 512, 64);
  combine8<<<dim3(128), 256, 0, stream>>>(QP, Ws_b, Wh_b, Q, 512, 32768);

  // fused attention GEMM + score epilogue
  mfma_gemm<128, 4, true><<<dim3(200, 4), 256, 0, stream>>>(enc, Wh_w, 1024, Q, vatt, PART, 0);
  softmax_s<<<dim3(64), 256, 0, stream>>>(PART, mask, flag, attn);
  ctx_kernel<<<dim3(64, 4), 256, 0, stream>>>(attn, enc, ctx, CONCAT);

  // out = concat@V_w^T + V_b
  sgemm_part<<<dim3(8, 8, 1), 256, 0, stream>>>(CONCAT, CONCAT, V_w, V_w, OUTP, OUTP, 1536, 512, 192);
  combine8<<<dim3(128), 256, 0, stream>>>(OUTP, V_b, nullptr, OUT, 512, 32768);

  // logits = out@Vhat^T + Vhat_b  (into d_out vocab region), then in-place softmax
  mfma_gemm<64, 2, false><<<dim3(1, 250), 256, 0, stream>>>(OUT, Vhat_w, 512, nullptr, Vhat_b, vocab, VVOC);
  vsoftmax<<<dim3(64), 256, 0, stream>>>(vocab);
}